// Round 3
// baseline (1075.017 us; speedup 1.0000x reference)
//
#include <hip/hip_runtime.h>
#include <hip/hip_bf16.h>
#include <stdint.h>

#define GLOBAL_AS __attribute__((address_space(1)))
#define LDS_AS    __attribute__((address_space(3)))

typedef __attribute__((ext_vector_type(8))) short  short8;   // 8 x bf16 bits (4 VGPRs)
typedef __attribute__((ext_vector_type(4))) float  floatx4;  // MFMA C/D

constexpr int BATCH = 8192;
constexpr int OUT   = 2048;
constexpr int KDIM  = 4096;   // INPUT+OUTPUT
constexpr int BM    = 128;    // batch rows per block
constexpr int BO    = 32;     // per-gate out cols per block; BN = 4*BO = 128
constexpr int BK    = 32;     // k per stage

__device__ __forceinline__ unsigned int cvt2(float a, float b) {
    union { __hip_bfloat162 h; unsigned int u; } v;
    v.h = __float22bfloat162_rn(make_float2(a, b));   // v_cvt_pk_bf16_f32 on gfx950
    return v.u;
}
__device__ __forceinline__ float sigmoidf_(float x) {
    return 1.0f / (1.0f + __expf(-x));
}
__device__ __forceinline__ void load_lds16(const unsigned short* g, unsigned short* l) {
    __builtin_amdgcn_global_load_lds((const GLOBAL_AS uint32_t*)g,
                                     (LDS_AS uint32_t*)l, 16, 0, 0);
}

// ---------------- phase 1: f32 -> bf16 conversion into workspace ----------------

__global__ __launch_bounds__(256)
void cvt_ih(const float* __restrict__ I, const float* __restrict__ H,
            unsigned short* __restrict__ dst)
{
    const size_t t = (size_t)blockIdx.x * 256 + threadIdx.x;   // 4,194,304 threads
    const size_t e = t * 8;
    const int b = (int)(e >> 12);          // row (4096 elems/row)
    const int k = (int)(e & 4095);
    const float* s = (k < 2048) ? (I + (size_t)b * 2048 + k)
                                : (H + (size_t)b * 2048 + (k - 2048));
    const float4 x = ((const float4*)s)[0];
    const float4 y = ((const float4*)s)[1];
    uint4 o;
    o.x = cvt2(x.x, x.y); o.y = cvt2(x.z, x.w);
    o.z = cvt2(y.x, y.y); o.w = cvt2(y.z, y.w);
    *(uint4*)(dst + e) = o;
}

__global__ __launch_bounds__(256)
void cvt_w(const float* __restrict__ W1, const float* __restrict__ W2,
           const float* __restrict__ W3, const float* __restrict__ W4,
           unsigned short* __restrict__ dst)
{
    const size_t t = (size_t)blockIdx.x * 256 + threadIdx.x;   // 4,194,304 threads
    const size_t e = t * 8;
    const int g = (int)(e >> 23);          // / (2048*4096)
    const size_t rem = e & 8388607u;
    const float* Wg = (g == 0) ? W1 : (g == 1) ? W2 : (g == 2) ? W3 : W4;
    const float* s = Wg + rem;
    const float4 x = ((const float4*)s)[0];
    const float4 y = ((const float4*)s)[1];
    uint4 o;
    o.x = cvt2(x.x, x.y); o.y = cvt2(x.z, x.w);
    o.z = cvt2(y.x, y.y); o.w = cvt2(y.z, y.w);
    *(uint4*)(dst + e) = o;
}

// ---------------- phase 2: bf16 GEMM (from ws) + fused LSTM epilogue ----------------
// ihb: [8192][4096] bf16; Wb: [4*2048][4096] bf16 (gate-major).
// LDS swizzle: data(row,kc) stored at chunk slot row*4 + (kc ^ ((row>>1)&3)); 16B chunks.

__global__ __launch_bounds__(256)
void lstm_gemm_ws(const unsigned short* __restrict__ ihb,
                  const unsigned short* __restrict__ Wb,
                  const float* __restrict__ C,
                  const float* __restrict__ B1, const float* __restrict__ B2,
                  const float* __restrict__ B3, const float* __restrict__ B4,
                  float* __restrict__ Outp)
{
    __shared__ unsigned short As[BM * BK];        // 8 KB
    __shared__ unsigned short Bs[4 * BO * BK];    // 8 KB

    const int tid  = threadIdx.x;
    const int w    = tid >> 6;
    const int lane = tid & 63;
    const int col  = lane & 15;
    const int q    = lane >> 4;

    const int bm0 = blockIdx.y * BM;
    const int o0  = blockIdx.x * BO;

    // staging: 8 windows of 64 chunks; wave w owns windows 2w, 2w+1
    long aoff[2], boff[2];
    unsigned short* ldsA[2];
    unsigned short* ldsB[2];
    #pragma unroll
    for (int j = 0; j < 2; ++j) {
        const int win = w * 2 + j;
        const int c   = win * 64 + lane;          // chunk id == slot row*4+kcs
        const int row = c >> 2;
        const int kcs = c & 3;
        const int kc  = kcs ^ ((row >> 1) & 3);   // un-swizzle: source k-chunk
        aoff[j] = (long)(bm0 + row) * KDIM + kc * 8;
        const int wrow = (row >> 5) * OUT + o0 + (row & 31);   // gate-major W row
        boff[j] = (long)wrow * KDIM + kc * 8;
        ldsA[j] = As + (size_t)win * 512;         // + lane*16B done by HW
        ldsB[j] = Bs + (size_t)win * 512;
    }

    // fragment LDS offsets (ushort units, 16B aligned)
    int aAddr[2];
    #pragma unroll
    for (int tm = 0; tm < 2; ++tm) {
        const int m = w * 32 + tm * 16 + col;
        aAddr[tm] = (m * 4 + (q ^ ((m >> 1) & 3))) * 8;
    }
    int bAddr[8];
    #pragma unroll
    for (int tn = 0; tn < 8; ++tn) {
        const int n = tn * 16 + col;
        bAddr[tn] = (n * 4 + (q ^ ((n >> 1) & 3))) * 8;
    }

    floatx4 acc[2][8];
    #pragma unroll
    for (int tm = 0; tm < 2; ++tm)
        #pragma unroll
        for (int tn = 0; tn < 8; ++tn)
            acc[tm][tn] = (floatx4){0.f, 0.f, 0.f, 0.f};

    for (int k0 = 0; k0 < KDIM; k0 += BK) {
        load_lds16(ihb + aoff[0] + k0, ldsA[0]);
        load_lds16(ihb + aoff[1] + k0, ldsA[1]);
        load_lds16(Wb  + boff[0] + k0, ldsB[0]);
        load_lds16(Wb  + boff[1] + k0, ldsB[1]);
        __syncthreads();

        const short8 a0 = *(const short8*)(As + aAddr[0]);
        const short8 a1 = *(const short8*)(As + aAddr[1]);
        #pragma unroll
        for (int tn = 0; tn < 8; ++tn) {
            const short8 b = *(const short8*)(Bs + bAddr[tn]);
            acc[0][tn] = __builtin_amdgcn_mfma_f32_16x16x32_bf16(a0, b, acc[0][tn], 0, 0, 0);
            acc[1][tn] = __builtin_amdgcn_mfma_f32_16x16x32_bf16(a1, b, acc[1][tn], 0, 0, 0);
        }
        __syncthreads();
    }

    // fused LSTM epilogue, in-register. acc[tm][g*2+obit][r]:
    //   b = bm0 + w*32 + tm*16 + q*4 + r,  o = o0 + obit*16 + col
    float bias[2][4];
    #pragma unroll
    for (int obit = 0; obit < 2; ++obit) {
        const int o = o0 + obit * 16 + col;
        bias[obit][0] = B1[o]; bias[obit][1] = B2[o];
        bias[obit][2] = B3[o]; bias[obit][3] = B4[o];
    }

    const size_t HALF = (size_t)BATCH * OUT;
    #pragma unroll
    for (int tm = 0; tm < 2; ++tm) {
        #pragma unroll
        for (int r = 0; r < 4; ++r) {
            const int b = bm0 + w * 32 + tm * 16 + q * 4 + r;
            #pragma unroll
            for (int obit = 0; obit < 2; ++obit) {
                const int o = o0 + obit * 16 + col;
                const size_t idx = (size_t)b * OUT + o;
                const float cv = C[idx];
                const float o1 = sigmoidf_(acc[tm][0 + obit][r] + bias[obit][0]);
                const float o2 = sigmoidf_(acc[tm][2 + obit][r] + bias[obit][1]);
                const float o3 = tanhf   (acc[tm][4 + obit][r] + bias[obit][2]);
                const float o4 = sigmoidf_(acc[tm][6 + obit][r] + bias[obit][3]);
                Outp[idx]        = tanhf(cv) * o4;        // new_h (OLD cell state)
                Outp[HALF + idx] = cv * o1 + o2 * o3;     // new_c
            }
        }
    }
}

// ---------------- fallback: single fused kernel, inline f32->bf16 ----------------

__global__ __launch_bounds__(256)
void lstm_fused_f32(const float* __restrict__ I, const float* __restrict__ H,
                    const float* __restrict__ C,
                    const float* __restrict__ W1, const float* __restrict__ B1,
                    const float* __restrict__ W2, const float* __restrict__ B2,
                    const float* __restrict__ W3, const float* __restrict__ B3,
                    const float* __restrict__ W4, const float* __restrict__ B4,
                    float* __restrict__ Outp)
{
    __shared__ unsigned short As[BM * BK];
    __shared__ unsigned short Bs[4 * BO * BK];

    const int tid  = threadIdx.x;
    const int w    = tid >> 6;
    const int lane = tid & 63;
    const int col  = lane & 15;
    const int q    = lane >> 4;

    const int bm0 = blockIdx.y * BM;
    const int o0  = blockIdx.x * BO;

    long aoff[2], boff[2];
    const float* wptr[2];
    unsigned short* dstA[2];
    unsigned short* dstB[2];
    #pragma unroll
    for (int j = 0; j < 2; ++j) {
        const int win = w * 2 + j;
        const int c   = win * 64 + lane;
        const int row = c >> 2;
        const int kcs = c & 3;
        const int kc  = kcs ^ ((row >> 1) & 3);
        aoff[j] = (long)(bm0 + row) * (KDIM / 2) + kc * 8;
        const int g = row >> 5;
        const int o = o0 + (row & 31);
        wptr[j] = (g == 0) ? W1 : (g == 1) ? W2 : (g == 2) ? W3 : W4;
        boff[j] = (long)o * KDIM + kc * 8;
        dstA[j] = As + (size_t)c * 8;
        dstB[j] = Bs + (size_t)c * 8;
    }

    int aAddr[2];
    #pragma unroll
    for (int tm = 0; tm < 2; ++tm) {
        const int m = w * 32 + tm * 16 + col;
        aAddr[tm] = (m * 4 + (q ^ ((m >> 1) & 3))) * 8;
    }
    int bAddr[8];
    #pragma unroll
    for (int tn = 0; tn < 8; ++tn) {
        const int n = tn * 16 + col;
        bAddr[tn] = (n * 4 + (q ^ ((n >> 1) & 3))) * 8;
    }

    floatx4 acc[2][8];
    #pragma unroll
    for (int tm = 0; tm < 2; ++tm)
        #pragma unroll
        for (int tn = 0; tn < 8; ++tn)
            acc[tm][tn] = (floatx4){0.f, 0.f, 0.f, 0.f};

    for (int k0 = 0; k0 < KDIM; k0 += BK) {
        #pragma unroll
        for (int j = 0; j < 2; ++j) {
            const float* ab = (k0 < KDIM / 2) ? (I + k0) : (H + (k0 - KDIM / 2));
            const float* sa = ab + aoff[j];
            const float* sb = wptr[j] + boff[j] + k0;
            const float4 a0 = ((const float4*)sa)[0];
            const float4 a1 = ((const float4*)sa)[1];
            const float4 b0 = ((const float4*)sb)[0];
            const float4 b1 = ((const float4*)sb)[1];
            uint4 va, vb;
            va.x = cvt2(a0.x, a0.y); va.y = cvt2(a0.z, a0.w);
            va.z = cvt2(a1.x, a1.y); va.w = cvt2(a1.z, a1.w);
            vb.x = cvt2(b0.x, b0.y); vb.y = cvt2(b0.z, b0.w);
            vb.z = cvt2(b1.x, b1.y); vb.w = cvt2(b1.z, b1.w);
            *(uint4*)dstA[j] = va;
            *(uint4*)dstB[j] = vb;
        }
        __syncthreads();

        const short8 a0 = *(const short8*)(As + aAddr[0]);
        const short8 a1 = *(const short8*)(As + aAddr[1]);
        #pragma unroll
        for (int tn = 0; tn < 8; ++tn) {
            const short8 b = *(const short8*)(Bs + bAddr[tn]);
            acc[0][tn] = __builtin_amdgcn_mfma_f32_16x16x32_bf16(a0, b, acc[0][tn], 0, 0, 0);
            acc[1][tn] = __builtin_amdgcn_mfma_f32_16x16x32_bf16(a1, b, acc[1][tn], 0, 0, 0);
        }
        __syncthreads();
    }

    float bias[2][4];
    #pragma unroll
    for (int obit = 0; obit < 2; ++obit) {
        const int o = o0 + obit * 16 + col;
        bias[obit][0] = B1[o]; bias[obit][1] = B2[o];
        bias[obit][2] = B3[o]; bias[obit][3] = B4[o];
    }

    const size_t HALF = (size_t)BATCH * OUT;
    #pragma unroll
    for (int tm = 0; tm < 2; ++tm) {
        #pragma unroll
        for (int r = 0; r < 4; ++r) {
            const int b = bm0 + w * 32 + tm * 16 + q * 4 + r;
            #pragma unroll
            for (int obit = 0; obit < 2; ++obit) {
                const int o = o0 + obit * 16 + col;
                const size_t idx = (size_t)b * OUT + o;
                const float cv = C[idx];
                const float o1 = sigmoidf_(acc[tm][0 + obit][r] + bias[obit][0]);
                const float o2 = sigmoidf_(acc[tm][2 + obit][r] + bias[obit][1]);
                const float o3 = tanhf   (acc[tm][4 + obit][r] + bias[obit][2]);
                const float o4 = sigmoidf_(acc[tm][6 + obit][r] + bias[obit][3]);
                Outp[idx]        = tanhf(cv) * o4;
                Outp[HALF + idx] = cv * o1 + o2 * o3;
            }
        }
    }
}

extern "C" void kernel_launch(void* const* d_in, const int* in_sizes, int n_in,
                              void* d_out, int out_size, void* d_ws, size_t ws_size,
                              hipStream_t stream) {
    const float* I  = (const float*)d_in[0];
    const float* H  = (const float*)d_in[1];
    const float* C  = (const float*)d_in[2];
    const float* W1 = (const float*)d_in[3];
    const float* B1 = (const float*)d_in[4];
    const float* W2 = (const float*)d_in[5];
    const float* B2 = (const float*)d_in[6];
    const float* W3 = (const float*)d_in[7];
    const float* B3 = (const float*)d_in[8];
    const float* W4 = (const float*)d_in[9];
    const float* B4 = (const float*)d_in[10];
    float* Outp = (float*)d_out;

    const size_t IH_ELEMS = (size_t)BATCH * KDIM;        // 33,554,432
    const size_t W_ELEMS  = (size_t)4 * OUT * KDIM;      // 33,554,432
    const size_t need     = (IH_ELEMS + W_ELEMS) * 2;    // 128 MiB bf16

    dim3 grid(OUT / BO, BATCH / BM);                     // (64, 64)

    if (ws_size >= need) {
        unsigned short* ihb = (unsigned short*)d_ws;
        unsigned short* Wb  = ihb + IH_ELEMS;
        cvt_ih<<<(int)(IH_ELEMS / 8 / 256), 256, 0, stream>>>(I, H, ihb);
        cvt_w <<<(int)(W_ELEMS  / 8 / 256), 256, 0, stream>>>(W1, W2, W3, W4, Wb);
        lstm_gemm_ws<<<grid, 256, 0, stream>>>(ihb, Wb, C, B1, B2, B3, B4, Outp);
    } else {
        lstm_fused_f32<<<grid, 256, 0, stream>>>(I, H, C, W1, B1, W2, B2,
                                                 W3, B3, W4, B4, Outp);
    }
}